// Round 1
// baseline (348.865 us; speedup 1.0000x reference)
//
#include <hip/hip_runtime.h>
#include <hip/hip_bf16.h>

// ---------------------------------------------------------------------------
// TransformerEncoder forward on MI355X (gfx950).
// Round 0: correctness-first baseline.
//   - all GEMMs via v_mfma_f32_16x16x32_bf16 (fp32 accum)
//   - weights transposed+converted to bf16 [N][K] in a prep pass
//   - attention: per-(head, 32-row) block, full softmax over 512 keys
// Workspace use: ~142 MB of d_ws.
// ---------------------------------------------------------------------------

typedef __bf16 bf16_t;
typedef __bf16 bf16x8 __attribute__((ext_vector_type(8)));
typedef float  f32x4  __attribute__((ext_vector_type(4)));

#define SEQL 512
#define DM   2048
#define FFH  8192
#define NH   16
#define DHD  128

__device__ __forceinline__ int swz4(int r){ return (r ^ (r >> 2)) & 3; }

__device__ __forceinline__ unsigned short bfbits(float f){
  bf16_t h = (bf16_t)f;
  return __builtin_bit_cast(unsigned short, h);
}
__device__ __forceinline__ unsigned int pack2(float a, float b){
  return (unsigned int)bfbits(a) | ((unsigned int)bfbits(b) << 16);
}

// ---------------------------------------------------------------------------
// fp32 -> bf16 elementwise convert (for `sequence`)
__global__ __launch_bounds__(256)
void cvt_bf16(const float* __restrict__ in, bf16_t* __restrict__ out){
  const int i = (blockIdx.x * 256 + threadIdx.x) * 4;
  const float4 v = *(const float4*)(in + i);
  ushort4 o;
  o.x = bfbits(v.x); o.y = bfbits(v.y); o.z = bfbits(v.z); o.w = bfbits(v.w);
  *(ushort4*)(out + i) = o;
}

// ---------------------------------------------------------------------------
// out[oR][oC] = in[src(oC)][oR], converted to bf16. out dims [inC][inR].
// perm=1 (Wo): src(k') = 16*(k'&127) + (k'>>7)  (row-permuted transpose so the
// attention output can be stored head-major [l][h*128+d]).
__global__ __launch_bounds__(256)
void transpose_bf16(const float* __restrict__ in, bf16_t* __restrict__ out,
                    int inR, int inC, int perm)
{
  __shared__ bf16_t t[64*65];
  const int tid = threadIdx.x;
  const int C0 = blockIdx.x * 64;   // over inR (input rows)
  const int R0 = blockIdx.y * 64;   // over inC (input cols)
#pragma unroll
  for (int it = 0; it < 4; ++it){
    const int i  = it*16 + (tid >> 4);
    const int j0 = (tid & 15) * 4;
    const int cc = C0 + i;
    const int srow = perm ? (((cc & 127) << 4) + (cc >> 7)) : cc;
    const float4 v = *(const float4*)(in + (size_t)srow * inC + R0 + j0);
    t[(j0+0)*65 + i] = (bf16_t)v.x;
    t[(j0+1)*65 + i] = (bf16_t)v.y;
    t[(j0+2)*65 + i] = (bf16_t)v.z;
    t[(j0+3)*65 + i] = (bf16_t)v.w;
  }
  __syncthreads();
#pragma unroll
  for (int it = 0; it < 2; ++it){
    const int r  = it*32 + (tid >> 3);
    const int c0 = (tid & 7) * 8;
    unsigned short us[8];
#pragma unroll
    for (int u = 0; u < 8; ++u) us[u] = __builtin_bit_cast(unsigned short, t[r*65 + c0 + u]);
    uint4 o;
    o.x = (unsigned)us[0] | ((unsigned)us[1] << 16);
    o.y = (unsigned)us[2] | ((unsigned)us[3] << 16);
    o.z = (unsigned)us[4] | ((unsigned)us[5] << 16);
    o.w = (unsigned)us[6] | ((unsigned)us[7] << 16);
    *(uint4*)(out + (size_t)(R0 + r) * inR + C0 + c0) = o;
  }
}

// ---------------------------------------------------------------------------
// Generic bt-GEMM: C[512][N] = A[512][K](bf16) @ BT[N][K](bf16)^T + bias, + epilogue
// BM=32, BN=64, BK=32, 128 threads (2 waves, each 32x32 via 2x2 16x16x32 frags)
constexpr int E_X    = 0;  // + posenc -> X fp32 + X bf16
constexpr int E_QK   = 1;  // -> flat bf16
constexpr int E_V    = 2;  // -> Vt[h][d][key] bf16
constexpr int E_AO   = 3;  // + resid fp32 -> fp32
constexpr int E_FFN1 = 4;  // gelu -> bf16
constexpr int E_FFN2 = 5;  // + resid fp32 -> fp32

template<int EPI>
__global__ __launch_bounds__(128)
void gemm_bt(const bf16_t* __restrict__ A, const bf16_t* __restrict__ BT,
             const float* __restrict__ bias, const float* __restrict__ resid,
             float* __restrict__ outF, bf16_t* __restrict__ outB,
             int N, int K)
{
  __shared__ bf16_t lA[32*32];
  __shared__ bf16_t lB[64*32];
  const int tid  = threadIdx.x;
  const int lane = tid & 63, w = tid >> 6;
  const int c = lane & 15, g = lane >> 4;
  const int m0 = blockIdx.y * 32, n0 = blockIdx.x * 64;

  // staging: 16B per thread from A, 2x16B from BT (rows k-contiguous)
  const int srow = tid >> 2, sslot = tid & 3;
  const size_t aoff  = (size_t)(m0 + srow) * K + sslot * 8;
  const size_t boff0 = (size_t)(n0 + srow) * K + sslot * 8;
  const size_t boff1 = (size_t)(n0 + srow + 32) * K + sslot * 8;
  const int wA  = srow*32 + ((sslot ^ swz4(srow)) << 3);
  const int wB0 = srow*32 + ((sslot ^ swz4(srow)) << 3);
  const int wB1 = (srow+32)*32 + ((sslot ^ swz4(srow+32)) << 3);

  int raddrA[2], raddrB[2];
#pragma unroll
  for (int a = 0; a < 2; ++a){ int r = a*16 + c;        raddrA[a] = r*32 + ((g ^ swz4(r)) << 3); }
#pragma unroll
  for (int b = 0; b < 2; ++b){ int r = w*32 + b*16 + c; raddrB[b] = r*32 + ((g ^ swz4(r)) << 3); }

  const int nk = K >> 5;
  uint4 pa  = *(const uint4*)(A  + aoff);
  uint4 pb0 = *(const uint4*)(BT + boff0);
  uint4 pb1 = *(const uint4*)(BT + boff1);

  f32x4 acc[2][2] = {};

  for (int kt = 0; kt < nk; ++kt){
    *(uint4*)&lA[wA]  = pa;
    *(uint4*)&lB[wB0] = pb0;
    *(uint4*)&lB[wB1] = pb1;
    __syncthreads();
    if (kt + 1 < nk){
      pa  = *(const uint4*)(A  + aoff  + (size_t)(kt+1)*32);
      pb0 = *(const uint4*)(BT + boff0 + (size_t)(kt+1)*32);
      pb1 = *(const uint4*)(BT + boff1 + (size_t)(kt+1)*32);
    }
    bf16x8 af0 = *(const bf16x8*)&lA[raddrA[0]];
    bf16x8 af1 = *(const bf16x8*)&lA[raddrA[1]];
    bf16x8 bf0 = *(const bf16x8*)&lB[raddrB[0]];
    bf16x8 bf1 = *(const bf16x8*)&lB[raddrB[1]];
    acc[0][0] = __builtin_amdgcn_mfma_f32_16x16x32_bf16(af0, bf0, acc[0][0], 0,0,0);
    acc[1][0] = __builtin_amdgcn_mfma_f32_16x16x32_bf16(af1, bf0, acc[1][0], 0,0,0);
    acc[0][1] = __builtin_amdgcn_mfma_f32_16x16x32_bf16(af0, bf1, acc[0][1], 0,0,0);
    acc[1][1] = __builtin_amdgcn_mfma_f32_16x16x32_bf16(af1, bf1, acc[1][1], 0,0,0);
    __syncthreads();
  }

  // epilogue: row = m0 + a*16 + 4g + rr, col = n0 + w*32 + b*16 + c
#pragma unroll
  for (int b = 0; b < 2; ++b){
    const int col = n0 + w*32 + b*16 + c;
    const float bv = bias[col];
#pragma unroll
    for (int a = 0; a < 2; ++a){
      const int row0 = m0 + a*16 + 4*g;
      if constexpr (EPI == E_V){
        const int hh = col & 15, dd = col >> 4;
        unsigned short us[4];
#pragma unroll
        for (int rr = 0; rr < 4; ++rr) us[rr] = bfbits(acc[a][b][rr] + bv);
        *(ushort4*)&outB[(size_t)(hh*DHD + dd)*SEQL + row0] =
            make_ushort4(us[0], us[1], us[2], us[3]);
      } else {
#pragma unroll
        for (int rr = 0; rr < 4; ++rr){
          const int row = row0 + rr;
          float v = acc[a][b][rr] + bv;
          if constexpr (EPI == E_X){
            const float fr  = 1e-4f * __expf(-(float)(col >> 1) * 0.0009765625f);
            const float ang = (float)row * fr;
            v += (col & 1) ? __cosf(ang) : __sinf(ang);
            outF[(size_t)row*N + col] = v;
            outB[(size_t)row*N + col] = (bf16_t)v;
          } else if constexpr (EPI == E_QK){
            outB[(size_t)row*N + col] = (bf16_t)v;
          } else if constexpr (EPI == E_AO || EPI == E_FFN2){
            outF[(size_t)row*N + col] = v + resid[(size_t)row*N + col];
          } else if constexpr (EPI == E_FFN1){
            const float z = v * (v*v*0.044715f + 1.0f) * 1.5957691216f;
            const float gg = v / (1.0f + __expf(-z));
            outB[(size_t)row*N + col] = (bf16_t)gg;
          }
        }
      }
    }
  }
}

// ---------------------------------------------------------------------------
// Gather Q/K flat [row][16d+h] -> head layout [h][row][d]; Q scaled by 1/sqrt(2048)
__global__ __launch_bounds__(256)
void permute_qk(const bf16_t* __restrict__ Qf, const bf16_t* __restrict__ Kf,
                bf16_t* __restrict__ Qhd, bf16_t* __restrict__ Khd)
{
  const int row = blockIdx.x, which = blockIdx.y, tid = threadIdx.x;
  const bf16_t* src = (which ? Kf : Qf) + (size_t)row * DM;
  bf16_t* dst = which ? Khd : Qhd;
  const int hh = tid >> 4, d0 = (tid & 15) * 8;
  const float scale = which ? 1.0f : 0.022097086912079612f;  // 1/sqrt(2048)
  float v[8];
#pragma unroll
  for (int j = 0; j < 8; ++j) v[j] = (float)src[(d0 + j)*NH + hh] * scale;
  uint4 o;
  o.x = pack2(v[0], v[1]); o.y = pack2(v[2], v[3]);
  o.z = pack2(v[4], v[5]); o.w = pack2(v[6], v[7]);
  *(uint4*)&dst[(size_t)hh*(SEQL*DHD) + (size_t)row*DHD + d0] = o;
}

// ---------------------------------------------------------------------------
// Attention: one block per (32 q-rows, head). Full softmax over 512 keys.
// Qh/Kh: [h][row][d]  Vt: [h][d][key]  Aout: [row][h*128+d] bf16
__global__ __launch_bounds__(256)
void attn_kernel(const bf16_t* __restrict__ Qh, const bf16_t* __restrict__ Kh,
                 const bf16_t* __restrict__ Vt, bf16_t* __restrict__ Aout)
{
  __shared__ bf16_t Pl[32*512];
  __shared__ float redm[4][32];
  __shared__ float reds[4][32];
  const int tid = threadIdx.x;
  const int lane = tid & 63, w = tid >> 6;
  const int c = lane & 15, g = lane >> 4;
  const int h = blockIdx.y;
  const int rb = blockIdx.x * 32;
  const bf16_t* Qb = Qh + (size_t)h * (SEQL*DHD);
  const bf16_t* Kb = Kh + (size_t)h * (SEQL*DHD);
  const bf16_t* Vb = Vt + (size_t)h * (SEQL*DHD);

  // Q fragments hoisted into registers
  bf16x8 qf[2][4];
#pragma unroll
  for (int a = 0; a < 2; ++a)
#pragma unroll
    for (int ks = 0; ks < 4; ++ks)
      qf[a][ks] = *(const bf16x8*)(Qb + (size_t)(rb + a*16 + c)*DHD + ks*32 + g*8);

  // S = Q K^T for this wave's 128 keys
  f32x4 s[2][8] = {};
#pragma unroll
  for (int ks = 0; ks < 4; ++ks)
#pragma unroll
    for (int b = 0; b < 8; ++b){
      const bf16x8 kf = *(const bf16x8*)(Kb + (size_t)(w*128 + b*16 + c)*DHD + ks*32 + g*8);
      s[0][b] = __builtin_amdgcn_mfma_f32_16x16x32_bf16(qf[0][ks], kf, s[0][b], 0,0,0);
      s[1][b] = __builtin_amdgcn_mfma_f32_16x16x32_bf16(qf[1][ks], kf, s[1][b], 0,0,0);
    }

  // softmax over keys (rows live at lr = a*16 + 4g + rr, keys at w*128+b*16+c)
  float mx[2][4], sm[2][4], inv[2][4];
#pragma unroll
  for (int a = 0; a < 2; ++a)
#pragma unroll
    for (int rr = 0; rr < 4; ++rr){
      float m = s[a][0][rr];
#pragma unroll
      for (int b = 1; b < 8; ++b) m = fmaxf(m, s[a][b][rr]);
#pragma unroll
      for (int off = 1; off < 16; off <<= 1) m = fmaxf(m, __shfl_xor(m, off));
      mx[a][rr] = m;
    }
  if (c == 0)
#pragma unroll
    for (int a = 0; a < 2; ++a)
#pragma unroll
      for (int rr = 0; rr < 4; ++rr) redm[w][a*16 + 4*g + rr] = mx[a][rr];
  __syncthreads();
#pragma unroll
  for (int a = 0; a < 2; ++a)
#pragma unroll
    for (int rr = 0; rr < 4; ++rr){
      const int lr = a*16 + 4*g + rr;
      mx[a][rr] = fmaxf(fmaxf(redm[0][lr], redm[1][lr]), fmaxf(redm[2][lr], redm[3][lr]));
      sm[a][rr] = 0.f;
    }
#pragma unroll
  for (int a = 0; a < 2; ++a)
#pragma unroll
    for (int b = 0; b < 8; ++b)
#pragma unroll
      for (int rr = 0; rr < 4; ++rr){
        const float p = __expf(s[a][b][rr] - mx[a][rr]);
        s[a][b][rr] = p;
        sm[a][rr] += p;
      }
#pragma unroll
  for (int a = 0; a < 2; ++a)
#pragma unroll
    for (int rr = 0; rr < 4; ++rr){
#pragma unroll
      for (int off = 1; off < 16; off <<= 1) sm[a][rr] += __shfl_xor(sm[a][rr], off);
    }
  if (c == 0)
#pragma unroll
    for (int a = 0; a < 2; ++a)
#pragma unroll
      for (int rr = 0; rr < 4; ++rr) reds[w][a*16 + 4*g + rr] = sm[a][rr];
  __syncthreads();
#pragma unroll
  for (int a = 0; a < 2; ++a)
#pragma unroll
    for (int rr = 0; rr < 4; ++rr){
      const int lr = a*16 + 4*g + rr;
      inv[a][rr] = 1.0f / (reds[0][lr] + reds[1][lr] + reds[2][lr] + reds[3][lr]);
    }

  // write P (bf16, XOR-swizzled 16B slots) to LDS for the PV A-operand
#pragma unroll
  for (int a = 0; a < 2; ++a)
#pragma unroll
    for (int b = 0; b < 8; ++b)
#pragma unroll
      for (int rr = 0; rr < 4; ++rr){
        const int lr  = a*16 + 4*g + rr;
        const int key = w*128 + b*16 + c;
        const int slot = (key >> 3) ^ (lr & 7);
        Pl[lr*512 + slot*8 + (key & 7)] = (bf16_t)(s[a][b][rr] * inv[a][rr]);
      }
  __syncthreads();

  // PV: wave w owns d-chunk dw = w*32
  f32x4 o[2][2] = {};
  const int dw = w * 32;
#pragma unroll
  for (int kst = 0; kst < 16; ++kst){
    bf16x8 pa2[2];
#pragma unroll
    for (int a = 0; a < 2; ++a){
      const int r = a*16 + c;
      const int slot = (kst*4 + g) ^ (r & 7);
      pa2[a] = *(const bf16x8*)&Pl[r*512 + slot*8];
    }
#pragma unroll
    for (int db = 0; db < 2; ++db){
      const bf16x8 vf = *(const bf16x8*)(Vb + (size_t)(dw + db*16 + c)*SEQL + kst*32 + g*8);
      o[0][db] = __builtin_amdgcn_mfma_f32_16x16x32_bf16(pa2[0], vf, o[0][db], 0,0,0);
      o[1][db] = __builtin_amdgcn_mfma_f32_16x16x32_bf16(pa2[1], vf, o[1][db], 0,0,0);
    }
  }
#pragma unroll
  for (int a = 0; a < 2; ++a)
#pragma unroll
    for (int db = 0; db < 2; ++db)
#pragma unroll
      for (int rr = 0; rr < 4; ++rr){
        const int row  = rb + a*16 + 4*g + rr;
        const int col2 = h*DHD + dw + db*16 + c;
        Aout[(size_t)row*DM + col2] = (bf16_t)o[a][db][rr];
      }
}

// ---------------------------------------------------------------------------
// Row LayerNorm over 2048. WB=1 additionally writes bf16 copy.
template<int WB>
__global__ __launch_bounds__(256)
void ln_kernel(const float* __restrict__ Y, const float* __restrict__ gam,
               const float* __restrict__ bet, float* __restrict__ outF,
               bf16_t* __restrict__ outB)
{
  const int row = blockIdx.x, tid = threadIdx.x;
  const float* x = Y + (size_t)row * DM;
  const float4 v0 = *(const float4*)(x + tid*8);
  const float4 v1 = *(const float4*)(x + tid*8 + 4);
  float s = v0.x+v0.y+v0.z+v0.w + v1.x+v1.y+v1.z+v1.w;
  float q = v0.x*v0.x+v0.y*v0.y+v0.z*v0.z+v0.w*v0.w
          + v1.x*v1.x+v1.y*v1.y+v1.z*v1.z+v1.w*v1.w;
#pragma unroll
  for (int off = 32; off >= 1; off >>= 1){ s += __shfl_xor(s, off); q += __shfl_xor(q, off); }
  __shared__ float rs[4], rq[4];
  const int w = tid >> 6;
  if ((tid & 63) == 0){ rs[w] = s; rq[w] = q; }
  __syncthreads();
  s = rs[0]+rs[1]+rs[2]+rs[3];
  q = rq[0]+rq[1]+rq[2]+rq[3];
  const float mu  = s * (1.0f/2048.0f);
  const float var = q * (1.0f/2048.0f) - mu*mu;
  const float rstd = rsqrtf(var + 1e-5f);
  const float4 g0 = *(const float4*)(gam + tid*8);
  const float4 g1 = *(const float4*)(gam + tid*8 + 4);
  const float4 b0 = *(const float4*)(bet + tid*8);
  const float4 b1 = *(const float4*)(bet + tid*8 + 4);
  float4 o0, o1;
  o0.x = (v0.x-mu)*rstd*g0.x + b0.x;  o0.y = (v0.y-mu)*rstd*g0.y + b0.y;
  o0.z = (v0.z-mu)*rstd*g0.z + b0.z;  o0.w = (v0.w-mu)*rstd*g0.w + b0.w;
  o1.x = (v1.x-mu)*rstd*g1.x + b1.x;  o1.y = (v1.y-mu)*rstd*g1.y + b1.y;
  o1.z = (v1.z-mu)*rstd*g1.z + b1.z;  o1.w = (v1.w-mu)*rstd*g1.w + b1.w;
  *(float4*)(outF + (size_t)row*DM + tid*8)     = o0;
  *(float4*)(outF + (size_t)row*DM + tid*8 + 4) = o1;
  if constexpr (WB){
    uint4 ob;
    ob.x = pack2(o0.x, o0.y); ob.y = pack2(o0.z, o0.w);
    ob.z = pack2(o1.x, o1.y); ob.w = pack2(o1.z, o1.w);
    *(uint4*)&outB[(size_t)row*DM + tid*8] = ob;
  }
}

// ---------------------------------------------------------------------------
extern "C" void kernel_launch(void* const* d_in, const int* in_sizes, int n_in,
                              void* d_out, int out_size, void* d_ws, size_t ws_size,
                              hipStream_t stream)
{
  const float* seq   = (const float*)d_in[0];
  const float* emb_W = (const float*)d_in[1];
  const float* emb_b = (const float*)d_in[2];
  const float* Wq = (const float*)d_in[3];  const float* bq = (const float*)d_in[4];
  const float* Wk = (const float*)d_in[5];  const float* bk = (const float*)d_in[6];
  const float* Wv = (const float*)d_in[7];  const float* bv = (const float*)d_in[8];
  const float* Wo = (const float*)d_in[9];  const float* bo = (const float*)d_in[10];
  const float* ln_g = (const float*)d_in[11]; const float* ln_b = (const float*)d_in[12];
  const float* W1 = (const float*)d_in[13]; const float* b1 = (const float*)d_in[14];
  const float* W2 = (const float*)d_in[15]; const float* b2 = (const float*)d_in[16];

  char* ws = (char*)d_ws;
  size_t off = 0;
  auto take = [&](size_t bytes) -> void* {
    void* p = ws + off;
    off += (bytes + 255) & ~(size_t)255;
    return p;
  };
  bf16_t* embT = (bf16_t*)take((size_t)DM*DM*2);
  bf16_t* WqT  = (bf16_t*)take((size_t)DM*DM*2);
  bf16_t* WkT  = (bf16_t*)take((size_t)DM*DM*2);
  bf16_t* WvT  = (bf16_t*)take((size_t)DM*DM*2);
  bf16_t* WoTp = (bf16_t*)take((size_t)DM*DM*2);
  bf16_t* W1T  = (bf16_t*)take((size_t)FFH*DM*2);
  bf16_t* W2T  = (bf16_t*)take((size_t)DM*FFH*2);
  bf16_t* seqB = (bf16_t*)take((size_t)SEQL*DM*2);
  float*  X    = (float*) take((size_t)SEQL*DM*4);
  bf16_t* XB   = (bf16_t*)take((size_t)SEQL*DM*2);
  bf16_t* Qf   = (bf16_t*)take((size_t)SEQL*DM*2);
  bf16_t* Kf   = (bf16_t*)take((size_t)SEQL*DM*2);
  bf16_t* Qhd  = (bf16_t*)take((size_t)SEQL*DM*2);
  bf16_t* Khd  = (bf16_t*)take((size_t)SEQL*DM*2);
  bf16_t* Vt   = (bf16_t*)take((size_t)SEQL*DM*2);
  bf16_t* Afl  = (bf16_t*)take((size_t)SEQL*DM*2);
  float*  Y    = (float*) take((size_t)SEQL*DM*4);
  float*  Xa   = (float*) take((size_t)SEQL*DM*4);
  bf16_t* XaB  = (bf16_t*)take((size_t)SEQL*DM*2);
  bf16_t* Hb   = (bf16_t*)take((size_t)SEQL*FFH*2);
  (void)ws_size; (void)in_sizes; (void)n_in; (void)out_size;

  // prep: converts + transposes
  cvt_bf16<<<dim3(SEQL*DM/1024), 256, 0, stream>>>(seq, seqB);
  transpose_bf16<<<dim3(32,32),  256, 0, stream>>>(emb_W, embT, DM, DM, 0);
  transpose_bf16<<<dim3(32,32),  256, 0, stream>>>(Wq, WqT, DM, DM, 0);
  transpose_bf16<<<dim3(32,32),  256, 0, stream>>>(Wk, WkT, DM, DM, 0);
  transpose_bf16<<<dim3(32,32),  256, 0, stream>>>(Wv, WvT, DM, DM, 0);
  transpose_bf16<<<dim3(32,32),  256, 0, stream>>>(Wo, WoTp, DM, DM, 1);
  transpose_bf16<<<dim3(32,128), 256, 0, stream>>>(W1, W1T, DM, FFH, 0);
  transpose_bf16<<<dim3(128,32), 256, 0, stream>>>(W2, W2T, FFH, DM, 0);

  // embedding + positional encoding
  gemm_bt<E_X><<<dim3(32,16), 128, 0, stream>>>(seqB, embT, emb_b, nullptr, X, XB, DM, DM);
  // QKV
  gemm_bt<E_QK><<<dim3(32,16), 128, 0, stream>>>(XB, WqT, bq, nullptr, nullptr, Qf, DM, DM);
  gemm_bt<E_QK><<<dim3(32,16), 128, 0, stream>>>(XB, WkT, bk, nullptr, nullptr, Kf, DM, DM);
  gemm_bt<E_V> <<<dim3(32,16), 128, 0, stream>>>(XB, WvT, bv, nullptr, nullptr, Vt, DM, DM);
  permute_qk<<<dim3(SEQL,2), 256, 0, stream>>>(Qf, Kf, Qhd, Khd);
  // attention
  attn_kernel<<<dim3(16,16), 256, 0, stream>>>(Qhd, Khd, Vt, Afl);
  // output proj + residual, LN1
  gemm_bt<E_AO><<<dim3(32,16), 128, 0, stream>>>(Afl, WoTp, bo, X, Y, nullptr, DM, DM);
  ln_kernel<1><<<SEQL, 256, 0, stream>>>(Y, ln_g, ln_b, Xa, XaB);
  // FFN
  gemm_bt<E_FFN1><<<dim3(128,16), 128, 0, stream>>>(XaB, W1T, b1, nullptr, nullptr, Hb, FFH, DM);
  gemm_bt<E_FFN2><<<dim3(32,16), 128, 0, stream>>>(Hb, W2T, b2, Xa, Y, nullptr, DM, FFH);
  ln_kernel<0><<<SEQL, 256, 0, stream>>>(Y, ln_g, ln_b, (float*)d_out, nullptr);
}